// Round 2
// baseline (3557.332 us; speedup 1.0000x reference)
//
#include <hip/hip_runtime.h>
#include <hip/hip_bf16.h>

// RecurrentActorCritic: B=512,T=512,S=64,H=128,A=8, all tensors fp32 (per reference).
// Grid: 512 blocks (one batch row each; GRU scan is batch-independent).
// Block: 384 threads (= 3H gate rows), __launch_bounds__(384,3) -> 2 blocks/CU.
// W_ih / W_hh rows live in VGPRs as packed fp16 pairs (values O(0.1-1): exact
// enough; fp32 accumulate via v_dot2_f32_f16 = 2 MAC/lane/cyc).

typedef _Float16 h2t __attribute__((ext_vector_type(2)));

__device__ __forceinline__ float dot2a(h2t a, h2t b, float c) {
#if defined(__has_builtin) && __has_builtin(__builtin_amdgcn_fdot2)
    return __builtin_amdgcn_fdot2(a, b, c, false);
#else
    return c + (float)a.x * (float)b.x + (float)a.y * (float)b.y;
#endif
}

#define BB 512
#define TT 512
#define SS 64
#define HH 128
#define G3 384
#define AA 8

__global__ __launch_bounds__(384, 3) void rac_kernel(
    const float* __restrict__ x,    // (B,T,S)
    const float* __restrict__ hx,   // (1,B,H)
    const int*   __restrict__ done, // (B,T)
    const float* __restrict__ Wf,   // (H,S)
    const float* __restrict__ bfe,  // (H)
    const float* __restrict__ gf,   // (H)
    const float* __restrict__ btf,  // (H)
    const float* __restrict__ Wih,  // (3H,H)
    const float* __restrict__ Whh,  // (3H,H)
    const float* __restrict__ bih,  // (3H)
    const float* __restrict__ bhh,  // (3H)
    const float* __restrict__ gr,   // (H)
    const float* __restrict__ btr,  // (H)
    const float* __restrict__ Wp,   // (A,H)
    const float* __restrict__ bp,   // (A)
    const float* __restrict__ Wv,   // (1,H)
    const float* __restrict__ bv,   // (1)
    float* __restrict__ out)
{
    const int tid = threadIdx.x;
    const int b   = blockIdx.x;

    // ---- LDS ----
    __shared__ __align__(16) h2t   wfeat[HH][SS/2 + 1]; // +1 pad: bank spread
    __shared__ __align__(16) float wpv[AA + 1][HH];     // W_pol rows + W_val row
    __shared__ float c_bf[HH], c_gf[HH], c_btf[HH], c_gr[HH], c_btr[HH];
    __shared__ float c_bih[G3], c_bhh[G3];
    __shared__ float c_bp[AA + 1];
    __shared__ __align__(16) _Float16 xh[SS];    // x_t as fp16
    __shared__ __align__(16) _Float16 zh[HH];    // z_t as fp16
    __shared__ __align__(16) _Float16 hsh[HH];   // h state as fp16 (dot input)
    __shared__ float gxl[G3], ghl[G3];
    __shared__ __align__(16) float yl[HH];
    __shared__ float red[4];
    __shared__ float dmask;

    // ---- register-resident recurrent weights (64 packed-fp16 VGPRs each) ----
    h2t wih_r[64], whh_r[64];
    {
        const float4* pih = (const float4*)(Wih + tid * HH);
        const float4* phh = (const float4*)(Whh + tid * HH);
        #pragma unroll
        for (int i = 0; i < 32; ++i) {
            float4 v = pih[i];
            h2t a, c;
            a.x = (_Float16)v.x; a.y = (_Float16)v.y;
            c.x = (_Float16)v.z; c.y = (_Float16)v.w;
            wih_r[2 * i] = a; wih_r[2 * i + 1] = c;
        }
        #pragma unroll
        for (int i = 0; i < 32; ++i) {
            float4 v = phh[i];
            h2t a, c;
            a.x = (_Float16)v.x; a.y = (_Float16)v.y;
            c.x = (_Float16)v.z; c.y = (_Float16)v.w;
            whh_r[2 * i] = a; whh_r[2 * i + 1] = c;
        }
    }

    // ---- LDS tables (one-time) ----
    for (int idx = tid; idx < HH * (SS / 2); idx += G3) {
        int r = idx >> 5, i = idx & 31;
        float2 v = ((const float2*)Wf)[r * 32 + i];
        h2t p; p.x = (_Float16)v.x; p.y = (_Float16)v.y;
        wfeat[r][i] = p;
    }
    for (int idx = tid; idx < (AA + 1) * HH; idx += G3) {
        int r = idx >> 7, c = idx & 127;
        wpv[r][c] = (r < AA) ? Wp[r * HH + c] : Wv[c];
    }
    if (tid < HH) {
        c_bf[tid]  = bfe[tid];
        c_gf[tid]  = gf[tid];
        c_btf[tid] = btf[tid];
        c_gr[tid]  = gr[tid];
        c_btr[tid] = btr[tid];
    }
    c_bih[tid] = bih[tid];
    c_bhh[tid] = bhh[tid];
    if (tid < AA) c_bp[tid] = bp[tid];
    if (tid == AA) c_bp[AA] = bv[0];

    float h_state = 0.f;
    if (tid < HH) {
        h_state = hx[b * HH + tid];
        hsh[tid] = (_Float16)h_state;
    }
    __syncthreads();

    const int VALO = BB * TT * AA;          // values offset
    const int HFIN = VALO + BB * TT;        // h_fin offset

    for (int t = 0; t < TT; ++t) {
        // ---- A: stage x_t (fp16) and done mask ----
        if (tid < SS) xh[tid] = (_Float16)x[(b * TT + t) * SS + tid];
        if (tid == SS) dmask = done[b * TT + t] ? 0.f : 1.f;
        __syncthreads();

        // ---- B: feature matvec + LayerNorm + ReLU ----
        float fv = 0.f;
        if (tid < HH) {
            const h2t* xv = (const h2t*)xh;
            fv = c_bf[tid];
            #pragma unroll
            for (int i = 0; i < SS / 2; ++i) fv = dot2a(wfeat[tid][i], xv[i], fv);
            float s = fv, q = fv * fv;
            #pragma unroll
            for (int m = 1; m < 64; m <<= 1) { s += __shfl_xor(s, m); q += __shfl_xor(q, m); }
            if ((tid & 63) == 0) { red[tid >> 6] = s; red[2 + (tid >> 6)] = q; }
        }
        __syncthreads();
        if (tid < HH) {
            float s = red[0] + red[1], q = red[2] + red[3];
            float mu = s * (1.f / 128.f);
            float rstd = rsqrtf(q * (1.f / 128.f) - mu * mu + 1e-5f);
            float z = (fv - mu) * rstd * c_gf[tid] + c_btf[tid];
            zh[tid] = (_Float16)fmaxf(z, 0.f);
        }
        __syncthreads();

        // ---- C: gate matvecs gx = W_ih@z, gh = W_hh@h (register weights) ----
        {
            const h2t* zv = (const h2t*)zh;
            const h2t* hv = (const h2t*)hsh;
            float gx = c_bih[tid], gh = c_bhh[tid];
            #pragma unroll
            for (int i = 0; i < 64; ++i) {
                gx = dot2a(wih_r[i], zv[i], gx);
                gh = dot2a(whh_r[i], hv[i], gh);
            }
            gxl[tid] = gx; ghl[tid] = gh;
        }
        __syncthreads();

        // ---- D: GRU gates + state update + LayerNorm(h_new) ----
        float hnew = 0.f;
        if (tid < HH) {
            float xr = gxl[tid],          hr = ghl[tid];
            float xz = gxl[HH + tid],     hz = ghl[HH + tid];
            float xn = gxl[2 * HH + tid], hn = ghl[2 * HH + tid];
            float r = 1.f / (1.f + __expf(-(xr + hr)));
            float u = 1.f / (1.f + __expf(-(xz + hz)));
            float a = xn + r * hn;
            a = fminf(fmaxf(a, -20.f), 20.f);
            float e2 = __expf(2.f * a);
            float n = (e2 - 1.f) / (e2 + 1.f);   // tanh
            hnew = (1.f - u) * n + u * h_state;
            float s = hnew, q = hnew * hnew;
            #pragma unroll
            for (int m = 1; m < 64; m <<= 1) { s += __shfl_xor(s, m); q += __shfl_xor(q, m); }
            if ((tid & 63) == 0) { red[tid >> 6] = s; red[2 + (tid >> 6)] = q; }
            float hm = hnew * dmask;             // done-mask reset for carry
            h_state = hm;
            hsh[tid] = (_Float16)hm;
            if (t == TT - 1) out[HFIN + b * HH + tid] = hm;
        }
        __syncthreads();
        if (tid < HH) {
            float s = red[0] + red[1], q = red[2] + red[3];
            float mu = s * (1.f / 128.f);
            float rstd = rsqrtf(q * (1.f / 128.f) - mu * mu + 1e-5f);
            yl[tid] = (hnew - mu) * rstd * c_gr[tid] + c_btr[tid];
        }
        __syncthreads();

        // ---- E: policy (8) + value (1) heads: 9 dots over H=128 ----
        if (tid < 288) {
            int o = tid >> 5, i = tid & 31;
            float4 yy = ((const float4*)yl)[i];
            float4 ww = ((const float4*)wpv[o])[i];
            float p = yy.x * ww.x + yy.y * ww.y + yy.z * ww.z + yy.w * ww.w;
            #pragma unroll
            for (int m = 16; m >= 1; m >>= 1) p += __shfl_xor(p, m);
            if (i == 0) {
                float v = p + c_bp[o];
                if (o < AA) out[(b * TT + t) * AA + o] = v;
                else        out[VALO + b * TT + t]     = v;
            }
        }
        __syncthreads();
    }
}

extern "C" void kernel_launch(void* const* d_in, const int* in_sizes, int n_in,
                              void* d_out, int out_size, void* d_ws, size_t ws_size,
                              hipStream_t stream) {
    const float* x   = (const float*)d_in[0];
    const float* hx  = (const float*)d_in[1];
    const int*   dn  = (const int*)d_in[2];
    const float* Wf  = (const float*)d_in[3];
    const float* bfe = (const float*)d_in[4];
    const float* gf  = (const float*)d_in[5];
    const float* btf = (const float*)d_in[6];
    const float* Wih = (const float*)d_in[7];
    const float* Whh = (const float*)d_in[8];
    const float* bih = (const float*)d_in[9];
    const float* bhh = (const float*)d_in[10];
    const float* gr  = (const float*)d_in[11];
    const float* btr = (const float*)d_in[12];
    const float* Wp  = (const float*)d_in[13];
    const float* bp  = (const float*)d_in[14];
    const float* Wv  = (const float*)d_in[15];
    const float* bv  = (const float*)d_in[16];
    float* out = (float*)d_out;

    hipLaunchKernelGGL(rac_kernel, dim3(BB), dim3(G3), 0, stream,
                       x, hx, dn, Wf, bfe, gf, btf, Wih, Whh, bih, bhh,
                       gr, btr, Wp, bp, Wv, bv, out);
}

// Round 3
// 1729.103 us; speedup vs baseline: 2.0573x; 2.0573x over previous
//
#include <hip/hip_runtime.h>

// RecurrentActorCritic B=512,T=512,S=64,H=128,A=8 (fp32 I/O).
// Grid 256 x 768 threads: one block per CU, TWO batch chains per block.
// Each thread owns ONE weight row in regs (64 h2t): tid<384 -> W_ih row tid;
// tid>=384 -> W_hh row tid-384. Threads 256-511 also own one W_feat row (32 h2t).
// R2 post-mortem: 128-row/thread layout spilled to scratch (VGPR_Count=84,
// 180 GB scratch traffic). One-row/thread keeps ~115 VGPR -> no spill.
// Pipeline (2 barriers/step): SegA: gx_t, gh_t matvecs + feature dots for
// z_{t+1} + y_{t-1} finalize + x(t+3) prefetch. SegB: z_{t+1} LN, GRU gates
// for t, heads for t-1, x(t+2) reg->LDS stage.

typedef _Float16 h2t __attribute__((ext_vector_type(2)));
typedef _Float16 h8t __attribute__((ext_vector_type(8)));

__device__ __forceinline__ float dot2a(h2t a, h2t b, float c) {
    return __builtin_amdgcn_fdot2(a, b, c, false);
}

#define BB 512
#define TT 512
#define SS 64
#define HH 128
#define AA 8
#define NT 768

__global__ __launch_bounds__(NT, 3) void rac_kernel(
    const float* __restrict__ x,    // (B,T,S)
    const float* __restrict__ hx,   // (1,B,H)
    const int*   __restrict__ done, // (B,T)
    const float* __restrict__ Wf,   // (H,S)
    const float* __restrict__ bfe,  // (H)
    const float* __restrict__ gf,   // (H)
    const float* __restrict__ btf,  // (H)
    const float* __restrict__ Wih,  // (3H,H)
    const float* __restrict__ Whh,  // (3H,H)
    const float* __restrict__ bih,  // (3H)
    const float* __restrict__ bhh,  // (3H)
    const float* __restrict__ gr,   // (H)
    const float* __restrict__ btr,  // (H)
    const float* __restrict__ Wp,   // (A,H)
    const float* __restrict__ bp,   // (A)
    const float* __restrict__ Wv,   // (1,H)
    const float* __restrict__ bv,   // (1)
    float* __restrict__ out)
{
    const int tid = threadIdx.x;
    const int b0  = blockIdx.x * 2;

    __shared__ __align__(16) _Float16 zh[2][HH];   // z_{t+1} (fp16)
    __shared__ __align__(16) _Float16 hsh[2][HH];  // h_{t-1} masked (fp16)
    __shared__ __align__(16) _Float16 xh[2][SS];   // x_{t+1} (fp16)
    __shared__ __align__(16) float gxl[2][3*HH];
    __shared__ __align__(16) float ghl[2][3*HH];
    __shared__ __align__(16) float yl[2][HH];      // y_{t-1}
    __shared__ __align__(16) float fraw[2][HH];    // raw feature pre-LN
    __shared__ float fred[4][2];                   // feature LN partials (waves 4-7)
    __shared__ float hred[4][2];                   // h LN partials (waves 0-3)

    const bool isGate = tid < 256;
    const bool isProd = tid < 384;
    const bool isFeat = (tid >= 256) && (tid < 512);
    const bool isXld  = (tid >= 512) && (tid < 640);
    const bool isHead = tid >= 512;

    // ---- one main matvec row per thread (64 h2t = 64 VGPR) ----
    h2t wmat[64];
    {
        const float* wsrc = isProd ? (Wih + tid * HH) : (Whh + (tid - 384) * HH);
        const float4* p = (const float4*)wsrc;
        #pragma unroll
        for (int q = 0; q < 32; ++q) {
            float4 v = p[q];
            h2t a; a.x = (_Float16)v.x; a.y = (_Float16)v.y;
            h2t b2; b2.x = (_Float16)v.z; b2.y = (_Float16)v.w;
            wmat[2 * q] = a; wmat[2 * q + 1] = b2;
        }
    }
    const float bias_mv = isProd ? bih[tid] : bhh[tid - 384];

    // ---- feature row (threads 256-511): 32 h2t ----
    h2t wfr[32];
    float bfr = 0.f;
    int fc = 0, fj = 0;
    if (isFeat) {
        fc = (tid - 256) >> 7; fj = (tid - 256) & 127;
        const float4* p = (const float4*)(Wf + fj * SS);
        #pragma unroll
        for (int q = 0; q < 16; ++q) {
            float4 v = p[q];
            h2t a; a.x = (_Float16)v.x; a.y = (_Float16)v.y;
            h2t b2; b2.x = (_Float16)v.z; b2.y = (_Float16)v.w;
            wfr[2 * q] = a; wfr[2 * q + 1] = b2;
        }
        bfr = bfe[fj];
    }

    // ---- gate-owner regs (threads 0-255: (chain gc, dim gj)) ----
    int gc = 0, gj = 0;
    float gfr = 0.f, btfr = 0.f, grr = 0.f, btrr = 0.f, hprev = 0.f;
    if (isGate) {
        gc = tid >> 7; gj = tid & 127;
        gfr = gf[gj]; btfr = btf[gj]; grr = gr[gj]; btrr = btr[gj];
        hprev = hx[(b0 + gc) * HH + gj];
        hsh[gc][gj] = (_Float16)hprev;
    }

    // ---- head regs (threads 512-767: 16 groups of 16; groups 0,1 take 2nd task) ----
    float wh0[8], wh1[8];
    float bp0 = 0.f, bp1 = 0.f;
    int hi16 = 0, tk0 = 0, tk1 = -1;
    if (isHead) {
        int hid = tid - 512; int hg = hid >> 4; hi16 = hid & 15;
        tk0 = hg;                       // tasks 0..15
        tk1 = (hg < 2) ? (16 + hg) : -1;  // tasks 16,17
        {
            int k = tk0 % 9;
            const float* wr = (k < 8) ? (Wp + k * HH) : Wv;
            #pragma unroll
            for (int e = 0; e < 8; ++e) wh0[e] = wr[hi16 * 8 + e];
            bp0 = (k < 8) ? bp[k] : bv[0];
        }
        if (tk1 >= 0) {
            int k = tk1 % 9;
            const float* wr = (k < 8) ? (Wp + k * HH) : Wv;
            #pragma unroll
            for (int e = 0; e < 8; ++e) wh1[e] = wr[hi16 * 8 + e];
            bp1 = (k < 8) ? bp[k] : bv[0];
        } else {
            #pragma unroll
            for (int e = 0; e < 8; ++e) wh1[e] = 0.f;
        }
    }

    // ---- x prefetch regs (threads 512-639) ----
    int xc = 0, xe = 0;
    const float* xbase = nullptr;
    float xr0 = 0.f, xr1 = 0.f;
    if (isXld) {
        int xi = tid - 512; xc = xi >> 6; xe = xi & 63;
        xbase = x + (size_t)(b0 + xc) * TT * SS + xe;
        float xa = xbase[0];            // x(0)
        xr1 = xbase[SS];                // x(1) held until P2
        xr0 = xbase[2 * SS];            // x(2), slot (0+2)&1 = 0
        xh[xc][xe] = (_Float16)xa;
    }
    __syncthreads();   // P0: xh=x0, hsh=hx visible

    // ---- prologue: z_0 ----
    if (isFeat) {
        float f0 = bfr, f1 = 0.f;
        const h8t* px = (const h8t*)xh[fc];
        #pragma unroll
        for (int k = 0; k < 8; ++k) {
            union { h8t v; h2t p[4]; } ux; ux.v = px[k];
            f0 = dot2a(wfr[4 * k + 0], ux.p[0], f0);
            f1 = dot2a(wfr[4 * k + 1], ux.p[1], f1);
            f0 = dot2a(wfr[4 * k + 2], ux.p[2], f0);
            f1 = dot2a(wfr[4 * k + 3], ux.p[3], f1);
        }
        float fv = f0 + f1;
        fraw[fc][fj] = fv;
        float s = fv, q = fv * fv;
        #pragma unroll
        for (int m = 1; m < 64; m <<= 1) { s += __shfl_xor(s, m); q += __shfl_xor(q, m); }
        if ((tid & 63) == 0) { int w = (tid >> 6) - 4; fred[w][0] = s; fred[w][1] = q; }
    }
    __syncthreads();   // P1
    if (isGate) {
        float s = fred[2 * gc][0] + fred[2 * gc + 1][0];
        float q = fred[2 * gc][1] + fred[2 * gc + 1][1];
        float mu = s * (1.f / 128.f);
        float rstd = rsqrtf(q * (1.f / 128.f) - mu * mu + 1e-5f);
        float z = (fraw[gc][gj] - mu) * rstd * gfr + btfr;
        zh[gc][gj] = (_Float16)fmaxf(z, 0.f);
    }
    if (isXld) xh[xc][xe] = (_Float16)xr1;   // stage x(1); xr1 now a free slot
    __syncthreads();   // P2

    float hnew_keep = 0.f;
    const int VALO = BB * TT * AA;
    const int HFIN = VALO + BB * TT;

    for (int i = 0; i <= TT; ++i) {
        const bool live = i < TT;
        // ================= Seg A =================
        int dreg = 0;
        if (isGate && live) dreg = done[(b0 + gc) * TT + i];
        if (isXld && i < TT - 3) {
            float v = xbase[(size_t)(i + 3) * SS];
            if (((i + 3) & 1) == 0) xr0 = v; else xr1 = v;
        }
        if (isGate && i >= 1) {   // finalize y_{i-1} from hred + kept h_new
            float s = hred[2 * gc][0] + hred[2 * gc + 1][0];
            float q = hred[2 * gc][1] + hred[2 * gc + 1][1];
            float mu = s * (1.f / 128.f);
            float rstd = rsqrtf(q * (1.f / 128.f) - mu * mu + 1e-5f);
            yl[gc][gj] = (hnew_keep - mu) * rstd * grr + btrr;
        }
        if (live) {   // main matvecs, both chains interleaved (ILP 2)
            const _Float16* va; const _Float16* vb; int r;
            if (isProd) { va = zh[0];  vb = zh[1];  r = tid; }
            else        { va = hsh[0]; vb = hsh[1]; r = tid - 384; }
            float a0 = bias_mv, a1 = bias_mv;
            const h8t* pa = (const h8t*)va; const h8t* pb = (const h8t*)vb;
            #pragma unroll
            for (int k = 0; k < 16; ++k) {
                union { h8t v; h2t p[4]; } ua, ub;
                ua.v = pa[k]; ub.v = pb[k];
                #pragma unroll
                for (int q = 0; q < 4; ++q) {
                    a0 = dot2a(wmat[4 * k + q], ua.p[q], a0);
                    a1 = dot2a(wmat[4 * k + q], ub.p[q], a1);
                }
            }
            if (isProd) { gxl[0][r] = a0; gxl[1][r] = a1; }
            else        { ghl[0][r] = a0; ghl[1][r] = a1; }
        }
        if (isFeat && i < TT - 1) {   // feature dots for z_{i+1} from xh=x_{i+1}
            float f0 = bfr, f1 = 0.f;
            const h8t* px = (const h8t*)xh[fc];
            #pragma unroll
            for (int k = 0; k < 8; ++k) {
                union { h8t v; h2t p[4]; } ux; ux.v = px[k];
                f0 = dot2a(wfr[4 * k + 0], ux.p[0], f0);
                f1 = dot2a(wfr[4 * k + 1], ux.p[1], f1);
                f0 = dot2a(wfr[4 * k + 2], ux.p[2], f0);
                f1 = dot2a(wfr[4 * k + 3], ux.p[3], f1);
            }
            float fv = f0 + f1;
            fraw[fc][fj] = fv;
            float s = fv, q = fv * fv;
            #pragma unroll
            for (int m = 1; m < 64; m <<= 1) { s += __shfl_xor(s, m); q += __shfl_xor(q, m); }
            if ((tid & 63) == 0) { int w = (tid >> 6) - 4; fred[w][0] = s; fred[w][1] = q; }
        }
        __syncthreads();
        // ================= Seg B =================
        if (isGate) {
            if (i < TT - 1) {   // LN+relu -> z_{i+1}
                float s = fred[2 * gc][0] + fred[2 * gc + 1][0];
                float q = fred[2 * gc][1] + fred[2 * gc + 1][1];
                float mu = s * (1.f / 128.f);
                float rstd = rsqrtf(q * (1.f / 128.f) - mu * mu + 1e-5f);
                float z = (fraw[gc][gj] - mu) * rstd * gfr + btfr;
                zh[gc][gj] = (_Float16)fmaxf(z, 0.f);
            }
            if (live) {         // GRU gates for step i
                float xr_ = gxl[gc][gj],          hr_ = ghl[gc][gj];
                float xz_ = gxl[gc][HH + gj],     hz_ = ghl[gc][HH + gj];
                float xn_ = gxl[gc][2 * HH + gj], hn_ = ghl[gc][2 * HH + gj];
                float r_ = 1.f / (1.f + __expf(-(xr_ + hr_)));
                float u_ = 1.f / (1.f + __expf(-(xz_ + hz_)));
                float a_ = xn_ + r_ * hn_;
                a_ = fminf(fmaxf(a_, -20.f), 20.f);
                float e2 = __expf(2.f * a_);
                float n_ = (e2 - 1.f) / (e2 + 1.f);
                float hn2 = (1.f - u_) * n_ + u_ * hprev;
                hnew_keep = hn2;
                float s = hn2, q = hn2 * hn2;
                #pragma unroll
                for (int m = 1; m < 64; m <<= 1) { s += __shfl_xor(s, m); q += __shfl_xor(q, m); }
                if ((tid & 63) == 0) { int w = tid >> 6; hred[w][0] = s; hred[w][1] = q; }
                float hm = hn2 * (dreg ? 0.f : 1.f);
                hprev = hm;
                hsh[gc][gj] = (_Float16)hm;
                if (i == TT - 1) out[HFIN + (b0 + gc) * HH + gj] = hm;
            }
        }
        if (isHead && i >= 1) {   // heads for t = i-1 from yl
            int t = i - 1;
            {
                int c = tk0 / 9, k = tk0 % 9;
                const float4* py = (const float4*)yl[c];
                float4 y0 = py[hi16 * 2], y1 = py[hi16 * 2 + 1];
                float p = y0.x * wh0[0] + y0.y * wh0[1] + y0.z * wh0[2] + y0.w * wh0[3]
                        + y1.x * wh0[4] + y1.y * wh0[5] + y1.z * wh0[6] + y1.w * wh0[7];
                #pragma unroll
                for (int m = 8; m >= 1; m >>= 1) p += __shfl_xor(p, m);
                if (hi16 == 0) {
                    int bc = b0 + c;
                    if (k < 8) out[((size_t)bc * TT + t) * AA + k] = p + bp0;
                    else       out[VALO + bc * TT + t] = p + bp0;
                }
            }
            if (tk1 >= 0) {
                int c = tk1 / 9, k = tk1 % 9;
                const float4* py = (const float4*)yl[c];
                float4 y0 = py[hi16 * 2], y1 = py[hi16 * 2 + 1];
                float p = y0.x * wh1[0] + y0.y * wh1[1] + y0.z * wh1[2] + y0.w * wh1[3]
                        + y1.x * wh1[4] + y1.y * wh1[5] + y1.z * wh1[6] + y1.w * wh1[7];
                #pragma unroll
                for (int m = 8; m >= 1; m >>= 1) p += __shfl_xor(p, m);
                if (hi16 == 0) {
                    int bc = b0 + c;
                    if (k < 8) out[((size_t)bc * TT + t) * AA + k] = p + bp1;
                    else       out[VALO + bc * TT + t] = p + bp1;
                }
            }
        }
        if (isXld && i < TT - 2) {   // stage x(i+2) reg -> LDS
            float v = (((i + 2) & 1) == 0) ? xr0 : xr1;
            xh[xc][xe] = (_Float16)v;
        }
        __syncthreads();
    }
}

extern "C" void kernel_launch(void* const* d_in, const int* in_sizes, int n_in,
                              void* d_out, int out_size, void* d_ws, size_t ws_size,
                              hipStream_t stream) {
    const float* x   = (const float*)d_in[0];
    const float* hx  = (const float*)d_in[1];
    const int*   dn  = (const int*)d_in[2];
    const float* Wf  = (const float*)d_in[3];
    const float* bfe = (const float*)d_in[4];
    const float* gf  = (const float*)d_in[5];
    const float* btf = (const float*)d_in[6];
    const float* Wih = (const float*)d_in[7];
    const float* Whh = (const float*)d_in[8];
    const float* bih = (const float*)d_in[9];
    const float* bhh = (const float*)d_in[10];
    const float* gr  = (const float*)d_in[11];
    const float* btr = (const float*)d_in[12];
    const float* Wp  = (const float*)d_in[13];
    const float* bp  = (const float*)d_in[14];
    const float* Wv  = (const float*)d_in[15];
    const float* bv  = (const float*)d_in[16];
    float* out = (float*)d_out;

    hipLaunchKernelGGL(rac_kernel, dim3(BB / 2), dim3(NT), 0, stream,
                       x, hx, dn, Wf, bfe, gf, btf, Wih, Whh, bih, bhh,
                       gr, btr, Wp, bp, Wv, bv, out);
}